// Round 2
// baseline (6735.800 us; speedup 1.0000x reference)
//
#include <hip/hip_runtime.h>
#include <hip/hip_bf16.h>

#define BM 64
#define BN 64
#define BK 16

// ---------------------------------------------------------------- gaussian smooth
#define GT 16
__global__ __launch_bounds__(256) void gauss_kernel(const float* __restrict__ X,
                                                    float* __restrict__ Y, int T) {
  int b = blockIdx.y, t0 = blockIdx.x * GT;
  int tid = threadIdx.x;  // d in [0,256)
  __shared__ float xs[GT + 19][256];
  const float* xb = X + (long)b * T * 256;
  for (int r = 0; r < GT + 19; ++r) {
    int tt = t0 + r - 9;
    xs[r][tid] = (tt >= 0 && tt < T) ? xb[(long)tt * 256 + tid] : 0.f;
  }
  __syncthreads();
  float g[20];
  float norm = 0.f;
#pragma unroll
  for (int j = 0; j < 20; ++j) {
    float u = (j - 9.5f) * 0.5f;
    g[j] = expf(-0.5f * u * u);
    norm += g[j];
  }
  float rn = 1.f / norm;
  for (int i = 0; i < GT; ++i) {
    int t = t0 + i;
    if (t >= T) break;
    float acc = 0.f;
#pragma unroll
    for (int j = 0; j < 20; ++j) acc += g[j] * xs[i + j][tid];
    Y[((long)b * T + t) * 256 + tid] = acc * rn;
  }
}

// ---------------------------------------------------------------- build fused 18-tap weights V
// V[u][g][d] = (u>=4 ? W1[g, d*14+u-4] : 0) + (u<14 ? W2[g, d*14+u] : 0)
__global__ void buildV_kernel(const float* __restrict__ w0, float* __restrict__ V) {
  long idx = (long)blockIdx.x * 256 + threadIdx.x;
  const long total = 18L * 1536 * 256;
  if (idx >= total) return;
  int u = (int)(idx / (1536 * 256));
  int r = (int)(idx % (1536 * 256));
  int g = r >> 8, d = r & 255;
  float v = 0.f;
  if (u < 14) v += w0[(long)g * 7168 + 3584 + d * 14 + u];
  if (u >= 4) v += w0[(long)g * 7168 + d * 14 + (u - 4)];
  V[idx] = v;
}

// ---------------------------------------------------------------- generic tap-GEMM
// Y[b,t,g] = bias[boff+g] + sum_tap sum_d W[wbase + g*wsg + tap*wst + d*wsd] * A[b, t*tstride + off(tap), d]
// off(tap) = tap*tap_scale + tap_off0 ; out-of-range time contributes 0.
__global__ __launch_bounds__(256) void qrnn_gemm(
    const float* __restrict__ A, const float* __restrict__ W,
    const float* __restrict__ bias, float* __restrict__ Y,
    const int* __restrict__ dayIdx, int Ta, int D, int Tm, int N, int tstride,
    int ntaps, int tap_scale, int tap_off0, long wsg, long wst, int wsd,
    long dayWStride, int dayBStride, int epilogue) {
  int b = blockIdx.z;
  int t0 = blockIdx.y * BM, g0 = blockIdx.x * BN;
  const float* Ab = A + (long)b * Ta * D;
  long wbase = 0;
  int boff = 0;
  if (dayIdx) {
    int di = dayIdx[b];
    wbase = (long)di * dayWStride;
    boff = di * dayBStride;
  }
  __shared__ float Al[BK][BM + 4];
  __shared__ float Wl[BK][BN + 4];
  int tid = threadIdx.x;
  int tx = tid & 15, ty = tid >> 4;
  float acc[4][4] = {};
  for (int tap = 0; tap < ntaps; ++tap) {
    int off = tap * tap_scale + tap_off0;
    for (int d0 = 0; d0 < D; d0 += BK) {
      // stage A tile (transposed into [k][m])
      {
        int r = tid >> 2, c4 = tid & 3;
        int t = t0 + r;
        int time = t * tstride + off;
        float4 v = {0.f, 0.f, 0.f, 0.f};
        if (t < Tm && time >= 0 && time < Ta)
          v = *reinterpret_cast<const float4*>(Ab + (long)time * D + d0 + c4 * 4);
        Al[c4 * 4 + 0][r] = v.x;
        Al[c4 * 4 + 1][r] = v.y;
        Al[c4 * 4 + 2][r] = v.z;
        Al[c4 * 4 + 3][r] = v.w;
      }
      // stage W tile into [k][n]
      if (wsd == 1) {
        int g = g0 + (tid >> 2), c4 = tid & 3;
        float4 v = *reinterpret_cast<const float4*>(W + wbase + (long)g * wsg +
                                                    (long)tap * wst + d0 + c4 * 4);
        Wl[c4 * 4 + 0][tid >> 2] = v.x;
        Wl[c4 * 4 + 1][tid >> 2] = v.y;
        Wl[c4 * 4 + 2][tid >> 2] = v.z;
        Wl[c4 * 4 + 3][tid >> 2] = v.w;
      } else {
        int dk = tid >> 4, gg = (tid & 15) * 4;
        float4 v = *reinterpret_cast<const float4*>(
            W + wbase + (long)(d0 + dk) * wsd + (long)tap * wst + g0 + gg);
        *reinterpret_cast<float4*>(&Wl[dk][gg]) = v;
      }
      __syncthreads();
#pragma unroll
      for (int k = 0; k < BK; ++k) {
        const float4 a = *reinterpret_cast<const float4*>(&Al[k][ty << 2]);
        const float4 w = *reinterpret_cast<const float4*>(&Wl[k][tx << 2]);
        acc[0][0] += a.x * w.x; acc[0][1] += a.x * w.y; acc[0][2] += a.x * w.z; acc[0][3] += a.x * w.w;
        acc[1][0] += a.y * w.x; acc[1][1] += a.y * w.y; acc[1][2] += a.y * w.z; acc[1][3] += a.y * w.w;
        acc[2][0] += a.z * w.x; acc[2][1] += a.z * w.y; acc[2][2] += a.z * w.z; acc[2][3] += a.z * w.w;
        acc[3][0] += a.w * w.x; acc[3][1] += a.w * w.y; acc[3][2] += a.w * w.z; acc[3][3] += a.w * w.w;
      }
      __syncthreads();
    }
  }
  const float4 bv = *reinterpret_cast<const float4*>(bias + boff + g0 + (tx << 2));
#pragma unroll
  for (int i = 0; i < 4; ++i) {
    int t = t0 + (ty << 2) + i;
    if (t >= Tm) continue;
    float4 v;
    v.x = acc[i][0] + bv.x;
    v.y = acc[i][1] + bv.y;
    v.z = acc[i][2] + bv.z;
    v.w = acc[i][3] + bv.w;
    if (epilogue == 1) {
      v.x = v.x / (1.f + fabsf(v.x));
      v.y = v.y / (1.f + fabsf(v.y));
      v.z = v.z / (1.f + fabsf(v.z));
      v.w = v.w / (1.f + fabsf(v.w));
    }
    *reinterpret_cast<float4*>(Y + ((long)b * Tm + t) * N + g0 + (tx << 2)) = v;
  }
}

// ---------------------------------------------------------------- t=0 overwrite (W1-only)
__global__ __launch_bounds__(256) void t0fix_kernel(const float* __restrict__ xs,
                                                    const float* __restrict__ w0,
                                                    const float* __restrict__ b0,
                                                    float* __restrict__ Y, int Tp) {
  int b = blockIdx.x / 24, gt = blockIdx.x % 24;
  int g0 = gt * 64;
  int tid = threadIdx.x;
  __shared__ float xls[3584];
  __shared__ float red[256];
  const float* xsB = xs + (long)b * 2000 * 256;  // rows 0..13 are contiguous
  for (int i = tid; i < 3584; i += 256) xls[i] = xsB[i];
  __syncthreads();
  int g = g0 + (tid >> 2);
  int part = tid & 3;
  const float* w0g = w0 + (long)g * 7168;
  float acc = 0.f;
  for (int j = part; j < 3584; j += 4) acc += w0g[j] * xls[(j % 14) * 256 + (j / 14)];
  red[tid] = acc;
  __syncthreads();
  if (part == 0) {
    float v = red[tid] + red[tid + 1] + red[tid + 2] + red[tid + 3];
    Y[(long)b * Tp * 1536 + g] = b0[g] + v;
  }
}

// ---------------------------------------------------------------- sequential scan
__global__ __launch_bounds__(256) void scan_kernel(const float* __restrict__ Yv,
                                                   float* __restrict__ Hout, int Tp) {
  int idx = blockIdx.x * 256 + threadIdx.x;  // 0..16383
  int b = idx >> 9, hh = idx & 511;
  const float* yb = Yv + (long)b * Tp * 1536 + hh;
  float* hb = Hout + (long)b * Tp * 512 + hh;
  float c = 0.f;
  float z = yb[0], f = yb[512], o = yb[1024];
  for (int t = 0; t < Tp; ++t) {
    float zn = 0.f, fn = 0.f, on = 0.f;
    if (t + 1 < Tp) {
      const float* p = yb + (long)(t + 1) * 1536;
      zn = p[0];
      fn = p[512];
      on = p[1024];
    }
    float fs = 1.f / (1.f + expf(-f));
    float zt = tanhf(z);
    c = fs * zt + (1.f - fs) * c;
    hb[(long)t * 512] = c / (1.f + expf(-o));
    z = zn;
    f = fn;
    o = on;
  }
}

// ---------------------------------------------------------------- layernorm + output GEMM
__global__ __launch_bounds__(256) void ln_out_kernel(
    const float* __restrict__ H, const float* __restrict__ gamma,
    const float* __restrict__ beta, const float* __restrict__ Wo,
    const float* __restrict__ bo, float* __restrict__ Out) {
  long bt = blockIdx.x;
  const float* hrow = H + bt * 512;
  int tid = threadIdx.x;
  float v0 = hrow[tid], v1 = hrow[tid + 256];
  float s = v0 + v1, s2 = v0 * v0 + v1 * v1;
#pragma unroll
  for (int d = 32; d; d >>= 1) {
    s += __shfl_down(s, d);
    s2 += __shfl_down(s2, d);
  }
  __shared__ float rs[4], rs2[4];
  int wid = tid >> 6, lane = tid & 63;
  if (lane == 0) {
    rs[wid] = s;
    rs2[wid] = s2;
  }
  __syncthreads();
  float sum = rs[0] + rs[1] + rs[2] + rs[3];
  float sum2 = rs2[0] + rs2[1] + rs2[2] + rs2[3];
  float mu = sum * (1.f / 512.f);
  float var = sum2 * (1.f / 512.f) - mu * mu;
  float rstd = rsqrtf(var + 1e-5f);
  __shared__ float hl[512];
  hl[tid] = (v0 - mu) * rstd * gamma[tid] + beta[tid];
  hl[tid + 256] = (v1 - mu) * rstd * gamma[tid + 256] + beta[tid + 256];
  __syncthreads();
  const float4* hp = reinterpret_cast<const float4*>(&hl[lane * 8]);
  float4 h0v = hp[0], h1v = hp[1];
  for (int c = wid; c < 41; c += 4) {
    const float4* wp = reinterpret_cast<const float4*>(Wo + (long)c * 512 + lane * 8);
    float4 w0v = wp[0], w1v = wp[1];
    float a = w0v.x * h0v.x + w0v.y * h0v.y + w0v.z * h0v.z + w0v.w * h0v.w +
              w1v.x * h1v.x + w1v.y * h1v.y + w1v.z * h1v.z + w1v.w * h1v.w;
#pragma unroll
    for (int d = 32; d; d >>= 1) a += __shfl_down(a, d);
    if (lane == 0) Out[bt * 41 + c] = a + bo[c];
  }
}

// ---------------------------------------------------------------- launch
extern "C" void kernel_launch(void* const* d_in, const int* in_sizes, int n_in,
                              void* d_out, int out_size, void* d_ws, size_t ws_size,
                              hipStream_t stream) {
  const float* neuralInput = (const float*)d_in[0];
  const int* dayIdx = (const int*)d_in[1];
  const float* dayWeights = (const float*)d_in[2];
  const float* dayBias = (const float*)d_in[3];
  const float* w0 = (const float*)d_in[4];
  const float* b0 = (const float*)d_in[5];
  const float* w_rest = (const float*)d_in[6];
  const float* b_rest = (const float*)d_in[7];
  const float* ln_gamma = (const float*)d_in[8];
  const float* ln_beta = (const float*)d_in[9];
  const float* w_out = (const float*)d_in[10];
  const float* b_out = (const float*)d_in[11];
  float* out = (float*)d_out;

  const int B = 32, T = 2000, D = 256, H = 512, Tp = 497;

  // workspace layout (floats). h1/h2 alias xs0 (dead after day GEMM).
  float* ws = (float*)d_ws;
  float* xs0 = ws;                       // [0, 16,384,000)
  float* h1 = ws;                        // reuses xs0: 8,142,848
  float* h2 = ws + 8142848L;             // reuses xs0: 8,142,848
  float* xs = ws + 16384000L;            // 16,384,000
  float* V = xs + 16384000L;             // 7,077,888
  float* y = V + 7077888L;               // 24,428,544  -> total 64,274,432 floats (257 MB)

  // 1. gaussian smooth
  {
    dim3 grid((T + GT - 1) / GT, B);
    hipLaunchKernelGGL(gauss_kernel, grid, dim3(256), 0, stream, neuralInput, xs0, T);
  }
  // 2. day GEMM + softsign : xs = softsign(xs0 @ Wd + bd)
  {
    dim3 grid(D / BN, (T + BM - 1) / BM, B);
    hipLaunchKernelGGL(qrnn_gemm, grid, dim3(256), 0, stream, xs0, dayWeights,
                       dayBias, xs, dayIdx, T, D, T, D, 1, 1, 0, 0, 1L, 0L, 256,
                       65536L, 256, 1);
  }
  // 3. build V
  {
    long total = 18L * 1536 * 256;
    hipLaunchKernelGGL(buildV_kernel, dim3((total + 255) / 256), dim3(256), 0,
                       stream, w0, V);
  }
  // 4. QRNN0 GEMM: y = V (*) xs + b0   (18 taps, stride 4)
  {
    dim3 grid(1536 / BN, (Tp + BM - 1) / BM, B);
    hipLaunchKernelGGL(qrnn_gemm, grid, dim3(256), 0, stream, xs, V, b0, y,
                       (const int*)nullptr, T, D, Tp, 1536, 4, 18, 1, -4, 256L,
                       393216L, 1, 0L, 0, 0);
  }
  // 5. overwrite t=0 with W1-only result
  hipLaunchKernelGGL(t0fix_kernel, dim3(B * 24), dim3(256), 0, stream, xs, w0, b0, y, Tp);
  // 6. scan 0
  hipLaunchKernelGGL(scan_kernel, dim3(B * H / 256), dim3(256), 0, stream, y, h1, Tp);
  // 7-10. layers 1,2  (feature dim per tap = H = 512; 2 taps cover [h_t, h_{t-1}])
  for (int i = 0; i < 2; ++i) {
    const float* hin = (i == 0) ? h1 : h2;
    float* hout = (i == 0) ? h2 : h1;
    dim3 grid(1536 / BN, (Tp + BM - 1) / BM, B);
    hipLaunchKernelGGL(qrnn_gemm, grid, dim3(256), 0, stream, hin,
                       w_rest + (long)i * 1536 * 1024, b_rest + (long)i * 1536, y,
                       (const int*)nullptr, Tp, H, Tp, 1536, 1, 2, -1, 0,
                       1024L, 512L, 1, 0L, 0, 0);
    hipLaunchKernelGGL(scan_kernel, dim3(B * H / 256), dim3(256), 0, stream, y, hout, Tp);
  }
  // 11. layernorm + output projection (h after layer 2 is in h1)
  hipLaunchKernelGGL(ln_out_kernel, dim3(B * Tp), dim3(256), 0, stream, h1,
                     ln_gamma, ln_beta, w_out, b_out, out);
}

// Round 3
// 1679.292 us; speedup vs baseline: 4.0111x; 4.0111x over previous
//
#include <hip/hip_runtime.h>
#include <hip/hip_bf16.h>

typedef __hip_bfloat16 bf16;
typedef __attribute__((ext_vector_type(8))) short bf16x8;
typedef __attribute__((ext_vector_type(4))) float f32x4;

// ---------------------------------------------------------------- gaussian smooth (bf16 out)
#define GT 16
__global__ __launch_bounds__(256) void gauss_kernel(const float* __restrict__ X,
                                                    bf16* __restrict__ Y, int T) {
  int b = blockIdx.y, t0 = blockIdx.x * GT;
  int tid = threadIdx.x;  // d in [0,256)
  __shared__ float xs[GT + 19][256];
  const float* xb = X + (long)b * T * 256;
  for (int r = 0; r < GT + 19; ++r) {
    int tt = t0 + r - 9;
    xs[r][tid] = (tt >= 0 && tt < T) ? xb[(long)tt * 256 + tid] : 0.f;
  }
  __syncthreads();
  float g[20];
  float norm = 0.f;
#pragma unroll
  for (int j = 0; j < 20; ++j) {
    float u = (j - 9.5f) * 0.5f;
    g[j] = expf(-0.5f * u * u);
    norm += g[j];
  }
  float rn = 1.f / norm;
  for (int i = 0; i < GT; ++i) {
    int t = t0 + i;
    if (t >= T) break;
    float acc = 0.f;
#pragma unroll
    for (int j = 0; j < 20; ++j) acc += g[j] * xs[i + j][tid];
    Y[((long)b * T + t) * 256 + tid] = (bf16)(acc * rn);
  }
}

// ---------------------------------------------------------------- dayWeights: fp32 [day][d][g] -> bf16 [day][g][d]
__global__ __launch_bounds__(256) void transpose_day(const float* __restrict__ W,
                                                     bf16* __restrict__ Wt) {
  __shared__ float tile[64][65];
  int d0 = blockIdx.x * 64, g0 = blockIdx.y * 64, day = blockIdx.z;
  const float* Wd = W + (long)day * 65536;
  int tx = threadIdx.x & 63, ty = threadIdx.x >> 6;
  for (int i = 0; i < 16; ++i) {
    int d = ty + i * 4;
    tile[d][tx] = Wd[(long)(d0 + d) * 256 + g0 + tx];
  }
  __syncthreads();
  bf16* out = Wt + (long)day * 65536;
  for (int i = 0; i < 16; ++i) {
    int g = ty + i * 4;
    out[(long)(g0 + g) * 256 + d0 + tx] = (bf16)tile[tx][g];
  }
}

// ---------------------------------------------------------------- build fused 18-tap weights V (bf16)
__global__ void buildV_kernel(const float* __restrict__ w0, bf16* __restrict__ V) {
  long idx = (long)blockIdx.x * 256 + threadIdx.x;
  const long total = 18L * 1536 * 256;
  if (idx >= total) return;
  int u = (int)(idx / (1536 * 256));
  int r = (int)(idx % (1536 * 256));
  int g = r >> 8, d = r & 255;
  float v = 0.f;
  if (u < 14) v += w0[(long)g * 7168 + 3584 + d * 14 + u];
  if (u >= 4) v += w0[(long)g * 7168 + d * 14 + (u - 4)];
  V[idx] = (bf16)v;
}

// ---------------------------------------------------------------- fp32 -> bf16 elementwise
__global__ void conv_bf16(const float* __restrict__ in, bf16* __restrict__ out, long n) {
  long i = (long)blockIdx.x * 256 + threadIdx.x;
  if (i < n) out[i] = (bf16)in[i];
}

// ---------------------------------------------------------------- MFMA tap-GEMM (bf16 in, fp32 acc)
// Y[b,t,g] = bias[boff+g] + sum_tap sum_d W[wbase+g*wsg+tap*wst+d] * A[b, t*tstride+off(tap), d]
// 128x128 tile, BK=64, 4 waves (64x64 each, 4x4 16x16 frags). XOR-swizzled LDS.
__global__ __launch_bounds__(256) void mfma_gemm(
    const bf16* __restrict__ A, const bf16* __restrict__ W,
    const float* __restrict__ bias, float* __restrict__ Yf,
    bf16* __restrict__ Yb, const int* __restrict__ dayIdx,
    int Ta, int D, int Tm, int N, int tstride, int ntaps, int tap_scale,
    int tap_off0, long wsg, long wst, long dayWStride, int dayBStride,
    int epilogue) {
  int b = blockIdx.z;
  int t0 = blockIdx.y * 128, g0 = blockIdx.x * 128;
  const bf16* Ab = A + (long)b * Ta * D;
  long wbase = 0;
  int boff = 0;
  if (dayIdx) {
    int di = dayIdx[b];
    wbase = (long)di * dayWStride;
    boff = di * dayBStride;
  }
  __shared__ __align__(16) bf16 Al[128 * 64];
  __shared__ __align__(16) bf16 Wl[128 * 64];
  int tid = threadIdx.x;
  int lane = tid & 63;
  int wave = tid >> 6;
  int wm = (wave >> 1) * 64, wn = (wave & 1) * 64;
  int lr = lane & 15, lg = lane >> 4;
  int srow = tid >> 3, su = tid & 7;
  f32x4 acc[4][4] = {};
  for (int tap = 0; tap < ntaps; ++tap) {
    int off = tap * tap_scale + tap_off0;
    const bf16* Wtap = W + wbase + (long)tap * wst;
    for (int d0 = 0; d0 < D; d0 += 64) {
      // stage A[128][64] and W[128][64], both [row][k], k contiguous, unit^=(row&7)
#pragma unroll
      for (int i = 0; i < 4; ++i) {
        int m = srow + i * 32;
        int t = t0 + m;
        int time = t * tstride + off;
        bf16x8 v = {};
        if (t < Tm && time >= 0 && time < Ta)
          v = *reinterpret_cast<const bf16x8*>(Ab + (long)time * D + d0 + su * 8);
        *reinterpret_cast<bf16x8*>(&Al[m * 64 + ((su ^ (m & 7)) << 3)]) = v;
        bf16x8 wv = *reinterpret_cast<const bf16x8*>(Wtap + (long)(g0 + m) * wsg + d0 + su * 8);
        *reinterpret_cast<bf16x8*>(&Wl[m * 64 + ((su ^ (m & 7)) << 3)]) = wv;
      }
      __syncthreads();
#pragma unroll
      for (int kc = 0; kc < 2; ++kc) {
        int ub = kc * 4 + lg;
        bf16x8 af[4], bw[4];
#pragma unroll
        for (int f = 0; f < 4; ++f) {
          int m = wm + f * 16 + lr;
          af[f] = *reinterpret_cast<const bf16x8*>(&Al[m * 64 + ((ub ^ (m & 7)) << 3)]);
          int g = wn + f * 16 + lr;
          bw[f] = *reinterpret_cast<const bf16x8*>(&Wl[g * 64 + ((ub ^ (g & 7)) << 3)]);
        }
#pragma unroll
        for (int fm = 0; fm < 4; ++fm)
#pragma unroll
          for (int fn = 0; fn < 4; ++fn)
            acc[fm][fn] = __builtin_amdgcn_mfma_f32_16x16x32_bf16(af[fm], bw[fn],
                                                                  acc[fm][fn], 0, 0, 0);
      }
      __syncthreads();
    }
  }
  // epilogue: D frag layout col=lane&15, row=(lane>>4)*4+r
#pragma unroll
  for (int fn = 0; fn < 4; ++fn) {
    int gcol = g0 + wn + fn * 16 + lr;
    float bb = bias[boff + gcol];
#pragma unroll
    for (int fm = 0; fm < 4; ++fm) {
#pragma unroll
      for (int r = 0; r < 4; ++r) {
        int t = t0 + wm + fm * 16 + lg * 4 + r;
        if (t >= Tm) continue;
        float v = acc[fm][fn][r] + bb;
        if (epilogue == 1) {
          v = v / (1.f + fabsf(v));
          Yb[((long)b * Tm + t) * N + gcol] = (bf16)v;
        } else {
          Yf[((long)b * Tm + t) * N + gcol] = v;
        }
      }
    }
  }
}

// ---------------------------------------------------------------- t=0 overwrite (W1-only)
__global__ __launch_bounds__(256) void t0fix_kernel(const bf16* __restrict__ xs,
                                                    const float* __restrict__ w0,
                                                    const float* __restrict__ b0,
                                                    float* __restrict__ Y, int Tp) {
  int b = blockIdx.x / 24, gt = blockIdx.x % 24;
  int g0 = gt * 64;
  int tid = threadIdx.x;
  __shared__ float xls[3584];
  __shared__ float red[256];
  const bf16* xsB = xs + (long)b * 2000 * 256;  // rows 0..13 contiguous
  for (int i = tid; i < 3584; i += 256) xls[i] = (float)xsB[i];
  __syncthreads();
  int g = g0 + (tid >> 2);
  int part = tid & 3;
  const float* w0g = w0 + (long)g * 7168;
  float acc = 0.f;
  for (int j = part; j < 3584; j += 4) acc += w0g[j] * xls[(j % 14) * 256 + (j / 14)];
  red[tid] = acc;
  __syncthreads();
  if (part == 0) {
    float v = red[tid] + red[tid + 1] + red[tid + 2] + red[tid + 3];
    Y[(long)b * Tp * 1536 + g] = b0[g] + v;
  }
}

// ---------------------------------------------------------------- sequential scan (fp32 in, bf16 out)
__global__ __launch_bounds__(256) void scan_kernel(const float* __restrict__ Yv,
                                                   bf16* __restrict__ Hout, int Tp) {
  int idx = blockIdx.x * 256 + threadIdx.x;  // 0..16383
  int b = idx >> 9, hh = idx & 511;
  const float* yb = Yv + (long)b * Tp * 1536 + hh;
  bf16* hb = Hout + (long)b * Tp * 512 + hh;
  float c = 0.f;
  float z = yb[0], f = yb[512], o = yb[1024];
  for (int t = 0; t < Tp; ++t) {
    float zn = 0.f, fn = 0.f, on = 0.f;
    if (t + 1 < Tp) {
      const float* p = yb + (long)(t + 1) * 1536;
      zn = p[0];
      fn = p[512];
      on = p[1024];
    }
    float fs = 1.f / (1.f + expf(-f));
    float zt = tanhf(z);
    c = fs * zt + (1.f - fs) * c;
    hb[(long)t * 512] = (bf16)(c / (1.f + expf(-o)));
    z = zn;
    f = fn;
    o = on;
  }
}

// ---------------------------------------------------------------- layernorm + output GEMM
__global__ __launch_bounds__(256) void ln_out_kernel(
    const bf16* __restrict__ H, const float* __restrict__ gamma,
    const float* __restrict__ beta, const float* __restrict__ Wo,
    const float* __restrict__ bo, float* __restrict__ Out) {
  long bt = blockIdx.x;
  const bf16* hrow = H + bt * 512;
  int tid = threadIdx.x;
  float v0 = (float)hrow[tid], v1 = (float)hrow[tid + 256];
  float s = v0 + v1, s2 = v0 * v0 + v1 * v1;
#pragma unroll
  for (int d = 32; d; d >>= 1) {
    s += __shfl_down(s, d);
    s2 += __shfl_down(s2, d);
  }
  __shared__ float rs[4], rs2[4];
  int wid = tid >> 6, lane = tid & 63;
  if (lane == 0) {
    rs[wid] = s;
    rs2[wid] = s2;
  }
  __syncthreads();
  float sum = rs[0] + rs[1] + rs[2] + rs[3];
  float sum2 = rs2[0] + rs2[1] + rs2[2] + rs2[3];
  float mu = sum * (1.f / 512.f);
  float var = sum2 * (1.f / 512.f) - mu * mu;
  float rstd = rsqrtf(var + 1e-5f);
  __shared__ float hl[512];
  hl[tid] = (v0 - mu) * rstd * gamma[tid] + beta[tid];
  hl[tid + 256] = (v1 - mu) * rstd * gamma[tid + 256] + beta[tid + 256];
  __syncthreads();
  const float4* hp = reinterpret_cast<const float4*>(&hl[lane * 8]);
  float4 h0v = hp[0], h1v = hp[1];
  for (int c = wid; c < 41; c += 4) {
    const float4* wp = reinterpret_cast<const float4*>(Wo + (long)c * 512 + lane * 8);
    float4 w0v = wp[0], w1v = wp[1];
    float a = w0v.x * h0v.x + w0v.y * h0v.y + w0v.z * h0v.z + w0v.w * h0v.w +
              w1v.x * h1v.x + w1v.y * h1v.y + w1v.z * h1v.z + w1v.w * h1v.w;
#pragma unroll
    for (int d = 32; d; d >>= 1) a += __shfl_down(a, d);
    if (lane == 0) Out[bt * 41 + c] = a + bo[c];
  }
}

// ---------------------------------------------------------------- launch
extern "C" void kernel_launch(void* const* d_in, const int* in_sizes, int n_in,
                              void* d_out, int out_size, void* d_ws, size_t ws_size,
                              hipStream_t stream) {
  const float* neuralInput = (const float*)d_in[0];
  const int* dayIdx = (const int*)d_in[1];
  const float* dayWeights = (const float*)d_in[2];
  const float* dayBias = (const float*)d_in[3];
  const float* w0 = (const float*)d_in[4];
  const float* b0 = (const float*)d_in[5];
  const float* w_rest = (const float*)d_in[6];
  const float* b_rest = (const float*)d_in[7];
  const float* ln_gamma = (const float*)d_in[8];
  const float* ln_beta = (const float*)d_in[9];
  const float* w_out = (const float*)d_in[10];
  const float* b_out = (const float*)d_in[11];
  float* out = (float*)d_out;

  const int B = 32, T = 2000, Tp = 497;

  char* p = (char*)d_ws;
  float* y = (float*)p;  p += 97714176;   // 32*497*1536 fp32
  bf16* xs0b = (bf16*)p; p += 32768000;   // 32*2000*256
  bf16* xs = (bf16*)p;   p += 32768000;   // 32*2000*256
  bf16* Vb = (bf16*)p;   p += 14155776;   // 18*1536*256
  bf16* dWb = (bf16*)p;  p += 3145728;    // 24*256*256
  bf16* wrb = (bf16*)p;  p += 6291456;    // 2*1536*1024
  bf16* h1 = (bf16*)p;   p += 16285696;   // 32*497*512
  bf16* h2 = (bf16*)p;   p += 16285696;   // 32*497*512

  // 1. gaussian smooth -> bf16
  hipLaunchKernelGGL(gauss_kernel, dim3((T + GT - 1) / GT, B), dim3(256), 0, stream,
                     neuralInput, xs0b, T);
  // 2. weight conversions
  hipLaunchKernelGGL(transpose_day, dim3(4, 4, 24), dim3(256), 0, stream, dayWeights, dWb);
  hipLaunchKernelGGL(buildV_kernel, dim3((18L * 1536 * 256 + 255) / 256), dim3(256), 0,
                     stream, w0, Vb);
  hipLaunchKernelGGL(conv_bf16, dim3((2L * 1536 * 1024 + 255) / 256), dim3(256), 0,
                     stream, w_rest, wrb, 2L * 1536 * 1024);
  // 3. day GEMM + softsign -> bf16 xs
  hipLaunchKernelGGL(mfma_gemm, dim3(2, 16, B), dim3(256), 0, stream, xs0b, dWb,
                     dayBias, (float*)nullptr, xs, dayIdx, T, 256, T, 256, 1, 1, 0, 0,
                     256L, 0L, 65536L, 256, 1);
  // 4. QRNN0 GEMM: y = V (*) xs + b0   (18 taps, stride 4)
  hipLaunchKernelGGL(mfma_gemm, dim3(12, 4, B), dim3(256), 0, stream, xs, Vb, b0, y,
                     (bf16*)nullptr, (const int*)nullptr, T, 256, Tp, 1536, 4, 18, 1,
                     -4, 256L, 1536L * 256, 0L, 0, 0);
  // 5. overwrite t=0 with W1-only result
  hipLaunchKernelGGL(t0fix_kernel, dim3(B * 24), dim3(256), 0, stream, xs, w0, b0, y, Tp);
  // 6. scan 0
  hipLaunchKernelGGL(scan_kernel, dim3(B * 512 / 256), dim3(256), 0, stream, y, h1, Tp);
  // 7-10. layers 1,2
  for (int i = 0; i < 2; ++i) {
    const bf16* hin = (i == 0) ? h1 : h2;
    bf16* hout = (i == 0) ? h2 : h1;
    hipLaunchKernelGGL(mfma_gemm, dim3(12, 4, B), dim3(256), 0, stream, hin,
                       wrb + (long)i * 1536 * 1024, b_rest + (long)i * 1536, y,
                       (bf16*)nullptr, (const int*)nullptr, Tp, 512, Tp, 1536, 1, 2,
                       -1, 0, 1024L, 512L, 0L, 0, 0);
    hipLaunchKernelGGL(scan_kernel, dim3(B * 512 / 256), dim3(256), 0, stream, y, hout, Tp);
  }
  // 11. layernorm + output projection (final h is in h1)
  hipLaunchKernelGGL(ln_out_kernel, dim3(B * Tp), dim3(256), 0, stream, h1,
                     ln_gamma, ln_beta, w_out, b_out, out);
}

// Round 5
// 944.358 us; speedup vs baseline: 7.1327x; 1.7782x over previous
//
#include <hip/hip_runtime.h>
#include <hip/hip_bf16.h>

typedef __hip_bfloat16 bf16;
typedef __attribute__((ext_vector_type(8))) short bf16x8;
typedef __attribute__((ext_vector_type(4))) float f32x4;

// ---------------------------------------------------------------- gaussian smooth (bf16 out)
#define GT 16
__global__ __launch_bounds__(256) void gauss_kernel(const float* __restrict__ X,
                                                    bf16* __restrict__ Y, int T) {
  int b = blockIdx.y, t0 = blockIdx.x * GT;
  int tid = threadIdx.x;  // d in [0,256)
  __shared__ float xs[GT + 19][256];
  const float* xb = X + (long)b * T * 256;
  for (int r = 0; r < GT + 19; ++r) {
    int tt = t0 + r - 9;
    xs[r][tid] = (tt >= 0 && tt < T) ? xb[(long)tt * 256 + tid] : 0.f;
  }
  __syncthreads();
  float g[20];
  float norm = 0.f;
#pragma unroll
  for (int j = 0; j < 20; ++j) {
    float u = (j - 9.5f) * 0.5f;
    g[j] = expf(-0.5f * u * u);
    norm += g[j];
  }
  float rn = 1.f / norm;
  for (int i = 0; i < GT; ++i) {
    int t = t0 + i;
    if (t >= T) break;
    float acc = 0.f;
#pragma unroll
    for (int j = 0; j < 20; ++j) acc += g[j] * xs[i + j][tid];
    Y[((long)b * T + t) * 256 + tid] = (bf16)(acc * rn);
  }
}

// ---------------------------------------------------------------- dayWeights: fp32 [day][d][g] -> bf16 [day][g][d]
__global__ __launch_bounds__(256) void transpose_day(const float* __restrict__ W,
                                                     bf16* __restrict__ Wt) {
  __shared__ float tile[64][65];
  int d0 = blockIdx.x * 64, g0 = blockIdx.y * 64, day = blockIdx.z;
  const float* Wd = W + (long)day * 65536;
  int tx = threadIdx.x & 63, ty = threadIdx.x >> 6;
  for (int i = 0; i < 16; ++i) {
    int d = ty + i * 4;
    tile[d][tx] = Wd[(long)(d0 + d) * 256 + g0 + tx];
  }
  __syncthreads();
  bf16* out = Wt + (long)day * 65536;
  for (int i = 0; i < 16; ++i) {
    int g = ty + i * 4;
    out[(long)(g0 + g) * 256 + d0 + tx] = (bf16)tile[tx][g];
  }
}

// ---------------------------------------------------------------- build fused 18-tap weights V (bf16)
__global__ void buildV_kernel(const float* __restrict__ w0, bf16* __restrict__ V) {
  long idx = (long)blockIdx.x * 256 + threadIdx.x;
  const long total = 18L * 1536 * 256;
  if (idx >= total) return;
  int u = (int)(idx / (1536 * 256));
  int r = (int)(idx % (1536 * 256));
  int g = r >> 8, d = r & 255;
  float v = 0.f;
  if (u < 14) v += w0[(long)g * 7168 + 3584 + d * 14 + u];
  if (u >= 4) v += w0[(long)g * 7168 + d * 14 + (u - 4)];
  V[idx] = (bf16)v;
}

// ---------------------------------------------------------------- w_rest -> bf16 with halves swapped (prev-part first)
__global__ void conv_wrest(const float* __restrict__ in, bf16* __restrict__ out, long n) {
  long i = (long)blockIdx.x * 256 + threadIdx.x;
  if (i >= n) return;
  long g = i >> 10;
  int k = (int)(i & 1023);
  out[i] = (bf16)in[(g << 10) | (long)(k ^ 512)];
}

// ---------------------------------------------------------------- w0 W1-half -> bf16 [1536][3584]
__global__ void conv_w0half(const float* __restrict__ in, bf16* __restrict__ out) {
  long i = (long)blockIdx.x * 256 + threadIdx.x;
  const long n = 1536L * 3584;
  if (i >= n) return;
  long g = i / 3584;
  int j = (int)(i - g * 3584);
  out[i] = (bf16)in[g * 7168 + j];
}

// ---------------------------------------------------------------- zero the per-b pad rows of h buffers
__global__ void zero_pads(bf16* __restrict__ h1s, bf16* __restrict__ h2s) {
  int i = blockIdx.x * 256 + threadIdx.x;  // 32*512
  if (i >= 16384) return;
  int b = i >> 9, k = i & 511;
  h1s[(long)b * 498 * 512 + k] = (bf16)0.f;
  h2s[(long)b * 498 * 512 + k] = (bf16)0.f;
}

// ---------------------------------------------------------------- MFMA tap-GEMM, dbuf-prefetched
// Y[b,t,g] = bias[boff+g] + sum_tap sum_d W[wbase+g*wsg+tap*wst+d] * A[b*astride + (t*tstride+tap+off0)*rstride + d]
__global__ __launch_bounds__(256) void mfma_gemm(
    const bf16* __restrict__ A, const bf16* __restrict__ W,
    const float* __restrict__ bias, float* __restrict__ Yf,
    bf16* __restrict__ Yb, const int* __restrict__ dayIdx,
    long astride, int Ta, int D, int rstride, int Tm, int N, int tstride,
    int ntaps, int tap_off0, long wsg, long wst, long dayWStride,
    int dayBStride, int epilogue) {
  int b = blockIdx.z;
  int t0 = blockIdx.y * 128, g0 = blockIdx.x * 128;
  const bf16* Ab = A + (long)b * astride;
  long wbase = 0;
  int boff = 0;
  if (dayIdx) {
    int di = dayIdx[b];
    wbase = (long)di * dayWStride;
    boff = di * dayBStride;
  }
  __shared__ __align__(16) bf16 Al[2][128 * 64];
  __shared__ __align__(16) bf16 Wl[2][128 * 64];
  int tid = threadIdx.x;
  int lane = tid & 63;
  int wave = tid >> 6;
  int wm = (wave >> 1) * 64, wn = (wave & 1) * 64;
  int lr = lane & 15, lg = lane >> 4;
  int srow = tid >> 3, su = tid & 7;
  int nch = D >> 6;
  int niter = ntaps * nch;
  f32x4 acc[4][4] = {};
  bf16x8 ra[4], rw[4];

  auto issue = [&](int it) {
    int tap = it / nch;
    int d0 = (it - tap * nch) << 6;
    int off = tap + tap_off0;
    const bf16* Wtap = W + wbase + (long)tap * wst;
#pragma unroll
    for (int i = 0; i < 4; ++i) {
      int m = srow + i * 32;
      int t = t0 + m;
      int time = t * tstride + off;
      bf16x8 v = {};
      if (t < Tm && time >= 0 && time < Ta)
        v = *reinterpret_cast<const bf16x8*>(Ab + (long)time * rstride + d0 + su * 8);
      ra[i] = v;
      rw[i] = *reinterpret_cast<const bf16x8*>(Wtap + (long)(g0 + m) * wsg + d0 + su * 8);
    }
  };
  auto write_lds = [&](int bufi) {
#pragma unroll
    for (int i = 0; i < 4; ++i) {
      int m = srow + i * 32;
      *reinterpret_cast<bf16x8*>(&Al[bufi][m * 64 + ((su ^ (m & 7)) << 3)]) = ra[i];
      *reinterpret_cast<bf16x8*>(&Wl[bufi][m * 64 + ((su ^ (m & 7)) << 3)]) = rw[i];
    }
  };

  issue(0);
  write_lds(0);
  __syncthreads();
  int cur = 0;
  for (int it = 0; it < niter; ++it) {
    if (it + 1 < niter) issue(it + 1);  // loads overlap compute below
#pragma unroll
    for (int kc = 0; kc < 2; ++kc) {
      int ub = kc * 4 + lg;
      bf16x8 af[4], bw[4];
#pragma unroll
      for (int f = 0; f < 4; ++f) {
        int m = wm + f * 16 + lr;
        af[f] = *reinterpret_cast<const bf16x8*>(&Al[cur][m * 64 + ((ub ^ (m & 7)) << 3)]);
        int g = wn + f * 16 + lr;
        bw[f] = *reinterpret_cast<const bf16x8*>(&Wl[cur][g * 64 + ((ub ^ (g & 7)) << 3)]);
      }
      __builtin_amdgcn_s_setprio(1);
#pragma unroll
      for (int fm = 0; fm < 4; ++fm)
#pragma unroll
        for (int fn = 0; fn < 4; ++fn)
          acc[fm][fn] = __builtin_amdgcn_mfma_f32_16x16x32_bf16(af[fm], bw[fn],
                                                                acc[fm][fn], 0, 0, 0);
      __builtin_amdgcn_s_setprio(0);
    }
    if (it + 1 < niter) write_lds(cur ^ 1);
    __syncthreads();
    cur ^= 1;
  }
#pragma unroll
  for (int fn = 0; fn < 4; ++fn) {
    int gcol = g0 + wn + fn * 16 + lr;
    float bb = bias[boff + gcol];
#pragma unroll
    for (int fm = 0; fm < 4; ++fm) {
#pragma unroll
      for (int r = 0; r < 4; ++r) {
        int t = t0 + wm + fm * 16 + lg * 4 + r;
        if (t >= Tm) continue;
        float v = acc[fm][fn][r] + bb;
        if (epilogue == 1) {
          v = v / (1.f + fabsf(v));
          Yb[((long)b * Tm + t) * N + gcol] = (bf16)v;
        } else {
          Yf[((long)b * Tm + t) * N + gcol] = v;
        }
      }
    }
  }
}

// ---------------------------------------------------------------- t=0 path: A0 im2col, GEMM partials, reduce
__global__ void build_A0(const bf16* __restrict__ xs, bf16* __restrict__ A0) {
  int idx = blockIdx.x * 256 + threadIdx.x;  // 32*3584
  if (idx >= 32 * 3584) return;
  int b = idx / 3584, j = idx % 3584;
  int d = j / 14, u = j % 14;
  A0[idx] = xs[((long)b * 2000 + u) * 256 + d];
}

__global__ __launch_bounds__(256) void t0_gemm(const bf16* __restrict__ A0,
                                               const bf16* __restrict__ W0b,
                                               float* __restrict__ part) {
  int g0 = blockIdx.x * 128;
  int ks = blockIdx.y;  // 0..6
  int k0 = ks * 512;
  __shared__ __align__(16) bf16 Wl[128 * 64];
  __shared__ __align__(16) bf16 Alds[32 * 64];
  int tid = threadIdx.x;
  int lane = tid & 63, wave = tid >> 6;
  int wn = wave * 32;
  int lr = lane & 15, lg = lane >> 4;
  int srow = tid >> 3, su = tid & 7;
  f32x4 acc[2][2] = {};
  for (int c = 0; c < 8; ++c) {
    int d0 = k0 + c * 64;
#pragma unroll
    for (int i = 0; i < 4; ++i) {
      int m = srow + i * 32;
      *reinterpret_cast<bf16x8*>(&Wl[m * 64 + ((su ^ (m & 7)) << 3)]) =
          *reinterpret_cast<const bf16x8*>(W0b + (long)(g0 + m) * 3584 + d0 + su * 8);
    }
    {
      int m = srow;  // 0..31
      *reinterpret_cast<bf16x8*>(&Alds[m * 64 + ((su ^ (m & 7)) << 3)]) =
          *reinterpret_cast<const bf16x8*>(A0 + (long)m * 3584 + d0 + su * 8);
    }
    __syncthreads();
#pragma unroll
    for (int kc = 0; kc < 2; ++kc) {
      int ub = kc * 4 + lg;
      bf16x8 am[2], bw[2];
#pragma unroll
      for (int f = 0; f < 2; ++f) {
        int m = f * 16 + lr;
        am[f] = *reinterpret_cast<const bf16x8*>(&Alds[m * 64 + ((ub ^ (m & 7)) << 3)]);
        int g = wn + f * 16 + lr;
        bw[f] = *reinterpret_cast<const bf16x8*>(&Wl[g * 64 + ((ub ^ (g & 7)) << 3)]);
      }
#pragma unroll
      for (int fm = 0; fm < 2; ++fm)
#pragma unroll
        for (int fn = 0; fn < 2; ++fn)
          acc[fm][fn] = __builtin_amdgcn_mfma_f32_16x16x32_bf16(am[fm], bw[fn],
                                                                acc[fm][fn], 0, 0, 0);
    }
    __syncthreads();
  }
#pragma unroll
  for (int fn = 0; fn < 2; ++fn) {
    int gcol = g0 + wn + fn * 16 + lr;
#pragma unroll
    for (int fm = 0; fm < 2; ++fm)
#pragma unroll
      for (int r = 0; r < 4; ++r) {
        int brow = fm * 16 + lg * 4 + r;
        part[((long)ks * 32 + brow) * 1536 + gcol] = acc[fm][fn][r];
      }
  }
}

__global__ void t0_reduce(const float* __restrict__ part, const float* __restrict__ b0,
                          float* __restrict__ y, int Tp) {
  int idx = blockIdx.x * 256 + threadIdx.x;  // 32*1536
  if (idx >= 32 * 1536) return;
  int b = idx / 1536, g = idx % 1536;
  float s = b0[g];
#pragma unroll
  for (int k = 0; k < 7; ++k) s += part[((long)k * 32 + b) * 1536 + g];
  y[(long)b * Tp * 1536 + g] = s;
}

// ---------------------------------------------------------------- chunked scan (3 passes)
#define NC 8
#define LC 63
__device__ __forceinline__ float fsig(float x) { return 1.f / (1.f + __expf(-x)); }
__device__ __forceinline__ float ftanh(float x) { return 1.f - 2.f / (1.f + __expf(2.f * x)); }

__global__ __launch_bounds__(256) void scan_pass1(const float* __restrict__ Yv,
                                                  float* __restrict__ Afac,
                                                  float* __restrict__ Bfac, int Tp) {
  int idx = blockIdx.x * 256 + threadIdx.x;  // 8*16384
  int ci = idx >> 14;
  int chain = idx & 16383;
  int b = chain >> 9, hh = chain & 511;
  const float* yb = Yv + (long)b * Tp * 1536 + hh;
  int t0 = ci * LC, t1 = min(t0 + LC, Tp);
  float A = 1.f, Bv = 0.f;
  for (int t = t0; t < t1; ++t) {
    const float* p = yb + (long)t * 1536;
    float z = p[0], f = p[512];
    float fs = fsig(f);
    Bv = fs * ftanh(z) + (1.f - fs) * Bv;
    A *= (1.f - fs);
  }
  Afac[idx] = A;
  Bfac[idx] = Bv;
}

__global__ void scan_pass2(const float* __restrict__ Afac, const float* __restrict__ Bfac,
                           float* __restrict__ cst) {
  int chain = blockIdx.x * 256 + threadIdx.x;  // 16384
  float c = 0.f;
#pragma unroll
  for (int ci = 0; ci < NC; ++ci) {
    cst[ci * 16384 + chain] = c;
    c = Afac[ci * 16384 + chain] * c + Bfac[ci * 16384 + chain];
  }
}

__global__ __launch_bounds__(256) void scan_pass3(const float* __restrict__ Yv,
                                                  const float* __restrict__ cst,
                                                  bf16* __restrict__ H, int Tp) {
  int idx = blockIdx.x * 256 + threadIdx.x;
  int ci = idx >> 14;
  int chain = idx & 16383;
  int b = chain >> 9, hh = chain & 511;
  const float* yb = Yv + (long)b * Tp * 1536 + hh;
  bf16* hb = H + ((long)b * 498 + 1) * 512 + hh;  // padded layout
  int t0 = ci * LC, t1 = min(t0 + LC, Tp);
  float c = cst[ci * 16384 + chain];
  for (int t = t0; t < t1; ++t) {
    const float* p = yb + (long)t * 1536;
    float z = p[0], f = p[512], o = p[1024];
    float fs = fsig(f);
    c = fs * ftanh(z) + (1.f - fs) * c;
    hb[(long)t * 512] = (bf16)(fsig(o) * c);
  }
}

// ---------------------------------------------------------------- layernorm + output GEMM
__global__ __launch_bounds__(256) void ln_out_kernel(
    const bf16* __restrict__ Hs, const float* __restrict__ gamma,
    const float* __restrict__ beta, const float* __restrict__ Wo,
    const float* __restrict__ bo, float* __restrict__ Out) {
  long bt = blockIdx.x;
  int b = (int)(bt / 497), t = (int)(bt % 497);
  const bf16* hrow = Hs + ((long)b * 498 + 1 + t) * 512;
  int tid = threadIdx.x;
  float v0 = (float)hrow[tid], v1 = (float)hrow[tid + 256];
  float s = v0 + v1, s2 = v0 * v0 + v1 * v1;
#pragma unroll
  for (int d = 32; d; d >>= 1) {
    s += __shfl_down(s, d);
    s2 += __shfl_down(s2, d);
  }
  __shared__ float rs[4], rs2[4];
  int wid = tid >> 6, lane = tid & 63;
  if (lane == 0) {
    rs[wid] = s;
    rs2[wid] = s2;
  }
  __syncthreads();
  float sum = rs[0] + rs[1] + rs[2] + rs[3];
  float sum2 = rs2[0] + rs2[1] + rs2[2] + rs2[3];
  float mu = sum * (1.f / 512.f);
  float var = sum2 * (1.f / 512.f) - mu * mu;
  float rstd = rsqrtf(var + 1e-5f);
  __shared__ float hl[512];
  hl[tid] = (v0 - mu) * rstd * gamma[tid] + beta[tid];
  hl[tid + 256] = (v1 - mu) * rstd * gamma[tid + 256] + beta[tid + 256];
  __syncthreads();
  const float4* hp = reinterpret_cast<const float4*>(&hl[lane * 8]);
  float4 h0v = hp[0], h1v = hp[1];
  for (int c = wid; c < 41; c += 4) {
    const float4* wp = reinterpret_cast<const float4*>(Wo + (long)c * 512 + lane * 8);
    float4 w0v = wp[0], w1v = wp[1];
    float a = w0v.x * h0v.x + w0v.y * h0v.y + w0v.z * h0v.z + w0v.w * h0v.w +
              w1v.x * h1v.x + w1v.y * h1v.y + w1v.z * h1v.z + w1v.w * h1v.w;
#pragma unroll
    for (int d = 32; d; d >>= 1) a += __shfl_down(a, d);
    if (lane == 0) Out[bt * 41 + c] = a + bo[c];
  }
}

// ---------------------------------------------------------------- launch
extern "C" void kernel_launch(void* const* d_in, const int* in_sizes, int n_in,
                              void* d_out, int out_size, void* d_ws, size_t ws_size,
                              hipStream_t stream) {
  const float* neuralInput = (const float*)d_in[0];
  const int* dayIdx = (const int*)d_in[1];
  const float* dayWeights = (const float*)d_in[2];
  const float* dayBias = (const float*)d_in[3];
  const float* w0 = (const float*)d_in[4];
  const float* b0 = (const float*)d_in[5];
  const float* w_rest = (const float*)d_in[6];
  const float* b_rest = (const float*)d_in[7];
  const float* ln_gamma = (const float*)d_in[8];
  const float* ln_beta = (const float*)d_in[9];
  const float* w_out = (const float*)d_in[10];
  const float* b_out = (const float*)d_in[11];
  float* out = (float*)d_out;

  const int B = 32, T = 2000, Tp = 497;

  char* p = (char*)d_ws;
  float* y = (float*)p;   p += 97714176;   // 32*497*1536 fp32
  bf16* xs0b = (bf16*)p;  p += 32768000;   // 32*2000*256
  bf16* xs = (bf16*)p;    p += 32768000;   // 32*2000*256
  bf16* Vb = (bf16*)p;    p += 14155776;   // 18*1536*256
  bf16* dWb = (bf16*)p;   p += 3145728;    // 24*256*256
  bf16* wrb = (bf16*)p;   p += 6291456;    // 2*1536*1024 (halves swapped)
  bf16* w0b = (bf16*)p;   p += 11010048;   // 1536*3584 (W1 half)
  bf16* A0 = (bf16*)p;    p += 229376;     // 32*3584
  float* part = (float*)p; p += 1376256;   // 7*32*1536
  bf16* h1s = (bf16*)p;   p += 16320512;   // 32*498*512 (per-b pad row)
  bf16* h2s = (bf16*)p;   p += 16320512;
  float* Afac = (float*)p; p += 524288;    // 8*16384
  float* Bfac = (float*)p; p += 524288;
  float* cst = (float*)p;  p += 524288;

  hipLaunchKernelGGL(zero_pads, dim3(64), dim3(256), 0, stream, h1s, h2s);
  hipLaunchKernelGGL(gauss_kernel, dim3((T + GT - 1) / GT, B), dim3(256), 0, stream,
                     neuralInput, xs0b, T);
  hipLaunchKernelGGL(transpose_day, dim3(4, 4, 24), dim3(256), 0, stream, dayWeights, dWb);
  hipLaunchKernelGGL(buildV_kernel, dim3((18L * 1536 * 256 + 255) / 256), dim3(256), 0,
                     stream, w0, Vb);
  hipLaunchKernelGGL(conv_wrest, dim3((2L * 1536 * 1024 + 255) / 256), dim3(256), 0,
                     stream, w_rest, wrb, 2L * 1536 * 1024);
  hipLaunchKernelGGL(conv_w0half, dim3((1536L * 3584 + 255) / 256), dim3(256), 0,
                     stream, w0, w0b);
  // day GEMM + softsign -> bf16 xs
  hipLaunchKernelGGL(mfma_gemm, dim3(2, 16, B), dim3(256), 0, stream, xs0b, dWb,
                     dayBias, (float*)nullptr, xs, dayIdx, (long)T * 256, T, 256, 256,
                     T, 256, 1, 1, 0, 256L, 0L, 65536L, 256, 1);
  // t=0 exact path
  hipLaunchKernelGGL(build_A0, dim3((32 * 3584 + 255) / 256), dim3(256), 0, stream, xs, A0);
  hipLaunchKernelGGL(t0_gemm, dim3(12, 7), dim3(256), 0, stream, A0, w0b, part);
  // QRNN0 fused 18-tap GEMM
  hipLaunchKernelGGL(mfma_gemm, dim3(12, 4, B), dim3(256), 0, stream, xs, Vb, b0, y,
                     (bf16*)nullptr, (const int*)nullptr, (long)T * 256, T, 256, 256,
                     Tp, 1536, 4, 18, -4, 256L, 1536L * 256, 0L, 0, 0);
  hipLaunchKernelGGL(t0_reduce, dim3((32 * 1536 + 255) / 256), dim3(256), 0, stream,
                     part, b0, y, Tp);
  // scan 0 -> h1
  hipLaunchKernelGGL(scan_pass1, dim3(512), dim3(256), 0, stream, y, Afac, Bfac, Tp);
  hipLaunchKernelGGL(scan_pass2, dim3(64), dim3(256), 0, stream, Afac, Bfac, cst);
  hipLaunchKernelGGL(scan_pass3, dim3(512), dim3(256), 0, stream, y, cst, h1s, Tp);
  // layers 1,2: single-tap K=1024 GEMM over padded h
  for (int i = 0; i < 2; ++i) {
    bf16* hin = (i == 0) ? h1s : h2s;
    bf16* hout = (i == 0) ? h2s : h1s;
    hipLaunchKernelGGL(mfma_gemm, dim3(12, 4, B), dim3(256), 0, stream, hin,
                       wrb + (long)i * 1536 * 1024, b_rest + (long)i * 1536, y,
                       (bf16*)nullptr, (const int*)nullptr, 498L * 512, Tp, 1024, 512,
                       Tp, 1536, 1, 1, 0, 1024L, 0L, 0L, 0, 0);
    hipLaunchKernelGGL(scan_pass1, dim3(512), dim3(256), 0, stream, y, Afac, Bfac, Tp);
    hipLaunchKernelGGL(scan_pass2, dim3(64), dim3(256), 0, stream, Afac, Bfac, cst);
    hipLaunchKernelGGL(scan_pass3, dim3(512), dim3(256), 0, stream, y, cst, hout, Tp);
  }
  // layernorm + output projection (final h is in h1s)
  hipLaunchKernelGGL(ln_out_kernel, dim3(B * Tp), dim3(256), 0, stream, h1s,
                     ln_gamma, ln_beta, w_out, b_out, out);
}

// Round 6
// 912.512 us; speedup vs baseline: 7.3816x; 1.0349x over previous
//
#include <hip/hip_runtime.h>
#include <hip/hip_bf16.h>

typedef __hip_bfloat16 bf16;
typedef __attribute__((ext_vector_type(8))) short bf16x8;
typedef __attribute__((ext_vector_type(4))) float f32x4;

// ---------------------------------------------------------------- gaussian smooth (bf16 out)
#define GT 16
__global__ __launch_bounds__(256) void gauss_kernel(const float* __restrict__ X,
                                                    bf16* __restrict__ Y, int T) {
  int b = blockIdx.y, t0 = blockIdx.x * GT;
  int tid = threadIdx.x;  // d in [0,256)
  __shared__ float xs[GT + 19][256];
  const float* xb = X + (long)b * T * 256;
  for (int r = 0; r < GT + 19; ++r) {
    int tt = t0 + r - 9;
    xs[r][tid] = (tt >= 0 && tt < T) ? xb[(long)tt * 256 + tid] : 0.f;
  }
  __syncthreads();
  float g[20];
  float norm = 0.f;
#pragma unroll
  for (int j = 0; j < 20; ++j) {
    float u = (j - 9.5f) * 0.5f;
    g[j] = expf(-0.5f * u * u);
    norm += g[j];
  }
  float rn = 1.f / norm;
  for (int i = 0; i < GT; ++i) {
    int t = t0 + i;
    if (t >= T) break;
    float acc = 0.f;
#pragma unroll
    for (int j = 0; j < 20; ++j) acc += g[j] * xs[i + j][tid];
    Y[((long)b * T + t) * 256 + tid] = (bf16)(acc * rn);
  }
}

// ---------------------------------------------------------------- dayWeights: fp32 [day][d][g] -> bf16 [day][g][d]
__global__ __launch_bounds__(256) void transpose_day(const float* __restrict__ W,
                                                     bf16* __restrict__ Wt) {
  __shared__ float tile[64][65];
  int d0 = blockIdx.x * 64, g0 = blockIdx.y * 64, day = blockIdx.z;
  const float* Wd = W + (long)day * 65536;
  int tx = threadIdx.x & 63, ty = threadIdx.x >> 6;
  for (int i = 0; i < 16; ++i) {
    int d = ty + i * 4;
    tile[d][tx] = Wd[(long)(d0 + d) * 256 + g0 + tx];
  }
  __syncthreads();
  bf16* out = Wt + (long)day * 65536;
  for (int i = 0; i < 16; ++i) {
    int g = ty + i * 4;
    out[(long)(g0 + g) * 256 + d0 + tx] = (bf16)tile[tx][g];
  }
}

// ---------------------------------------------------------------- build fused 18-tap weights V (bf16)
__global__ void buildV_kernel(const float* __restrict__ w0, bf16* __restrict__ V) {
  long idx = (long)blockIdx.x * 256 + threadIdx.x;
  const long total = 18L * 1536 * 256;
  if (idx >= total) return;
  int u = (int)(idx / (1536 * 256));
  int r = (int)(idx % (1536 * 256));
  int g = r >> 8, d = r & 255;
  float v = 0.f;
  if (u < 14) v += w0[(long)g * 7168 + 3584 + d * 14 + u];
  if (u >= 4) v += w0[(long)g * 7168 + d * 14 + (u - 4)];
  V[idx] = (bf16)v;
}

// ---------------------------------------------------------------- w_rest -> bf16 with halves swapped (prev-part first)
__global__ void conv_wrest(const float* __restrict__ in, bf16* __restrict__ out, long n) {
  long i = (long)blockIdx.x * 256 + threadIdx.x;
  if (i >= n) return;
  long g = i >> 10;
  int k = (int)(i & 1023);
  out[i] = (bf16)in[(g << 10) | (long)(k ^ 512)];
}

// ---------------------------------------------------------------- w0 W1-half -> bf16 [1536][3584]
__global__ void conv_w0half(const float* __restrict__ in, bf16* __restrict__ out) {
  long i = (long)blockIdx.x * 256 + threadIdx.x;
  const long n = 1536L * 3584;
  if (i >= n) return;
  long g = i / 3584;
  int j = (int)(i - g * 3584);
  out[i] = (bf16)in[g * 7168 + j];
}

// ---------------------------------------------------------------- zero pads + zero page
__global__ void zero_pads(bf16* __restrict__ h1s, bf16* __restrict__ h2s,
                          float* __restrict__ zpage) {
  int i = blockIdx.x * 256 + threadIdx.x;  // 32*512
  if (i < 64) zpage[i] = 0.f;
  if (i >= 16384) return;
  int b = i >> 9, k = i & 511;
  h1s[(long)b * 498 * 512 + k] = (bf16)0.f;
  h2s[(long)b * 498 * 512 + k] = (bf16)0.f;
}

// ---------------------------------------------------------------- 8-wave counted-vmcnt pipelined tap-GEMM
// BM=128 (t), BN=256 (g), K-step 64. 3 LDS buffers, global_load_lds staging,
// vmcnt(12) counted waits, raw s_barrier, read-side XOR swizzle via pre-swizzled source.
// Grid: 768 blocks = 8 XCD chunks x (6 g x 4 t x 4 b); b = xcd*4 + bi.
__global__ __launch_bounds__(512) void gemm8(
    const bf16* __restrict__ A, const bf16* __restrict__ W,
    const float* __restrict__ bias, float* __restrict__ Y,
    const bf16* __restrict__ zpage,
    long astride, int Ta, int D, int rstride, int Tm, int N, int tstride,
    int ntaps, int tap_off0, long wsg, long wst) {
  extern __shared__ char smem[];  // 3 * 49152 bytes
  const int id = blockIdx.x;
  const int xcd = id & 7, local = id >> 3;
  const int gi = local >> 4;            // 0..5
  const int ti = (local >> 2) & 3;      // 0..3
  const int bi = local & 3;             // 0..3
  const int b = xcd * 4 + bi;
  const int g0 = gi * 256, t0 = ti * 128;

  const bf16* Ab = A + (long)b * astride;
  const int tid = threadIdx.x;
  const int lane = tid & 63;
  const int w = tid >> 6;               // wave 0..7
  const int wr = w >> 2, wc = w & 3;    // 2M x 4N, wave tile 64x64
  const int lr = lane & 15, lg = lane >> 4;
  const int nch = D >> 6;
  const int ns = ntaps * nch;

  // stage K-step s into buffer bufi (6 global_load_lds per thread)
  auto stage = [&](int bufi, int s) {
    int tap = s / nch;
    int d0 = (s - tap * nch) << 6;
    const bf16* Wp = W + (long)tap * wst + d0;
    long base = (long)bufi * 49152;
#pragma unroll
    for (int j = 0; j < 6; ++j) {
      int q = j * 512 + tid;            // unit index (per-lane, for source addr)
      int qw = j * 512 + w * 64;        // wave-uniform LDS unit base
      const bf16* src;
      if (q < 1024) {                   // A: row = q>>3 (0..127), u = q&7
        int row = q >> 3;
        int u = (q & 7) ^ (row & 7);    // pre-swizzled source unit
        int time = (t0 + row) * tstride + tap + tap_off0;
        src = (time >= 0 && time < Ta)
                  ? Ab + (long)time * rstride + d0 + u * 8
                  : zpage;
      } else {                          // W: row = (q-1024)>>3 (0..255)
        int row = (q - 1024) >> 3;
        int u = (q & 7) ^ (row & 7);
        src = Wp + (long)(g0 + row) * wsg + u * 8;
      }
      auto lp = (__attribute__((address_space(3))) void*)(smem + base + (long)qw * 16);
      __builtin_amdgcn_global_load_lds(
          (const __attribute__((address_space(1))) void*)src, lp, 16, 0, 0);
    }
  };

  f32x4 acc[4][4] = {};

  stage(0, 0);
  if (ns > 1) stage(1, 1);
  for (int s = 0; s < ns; ++s) {
    int cur = s % 3;
    if (s + 2 < ns) {
      stage((s + 2) % 3, s + 2);
      asm volatile("s_waitcnt vmcnt(12)" ::: "memory");
    } else if (s + 1 < ns) {
      asm volatile("s_waitcnt vmcnt(6)" ::: "memory");
    } else {
      asm volatile("s_waitcnt vmcnt(0)" ::: "memory");
    }
    __builtin_amdgcn_s_barrier();
    __builtin_amdgcn_sched_barrier(0);
    const char* bufp = smem + (long)cur * 49152;
#pragma unroll
    for (int kc = 0; kc < 2; ++kc) {
      int ub = kc * 4 + lg;
      bf16x8 af[4], bw[4];
#pragma unroll
      for (int f = 0; f < 4; ++f) {
        int m = wr * 64 + f * 16 + lr;
        af[f] = *reinterpret_cast<const bf16x8*>(bufp + m * 128 + ((ub ^ (m & 7)) << 4));
        int g = wc * 64 + f * 16 + lr;
        bw[f] = *reinterpret_cast<const bf16x8*>(bufp + 16384 + g * 128 +
                                                 ((ub ^ (g & 7)) << 4));
      }
      __builtin_amdgcn_s_setprio(1);
#pragma unroll
      for (int fm = 0; fm < 4; ++fm)
#pragma unroll
        for (int fn = 0; fn < 4; ++fn)
          acc[fm][fn] = __builtin_amdgcn_mfma_f32_16x16x32_bf16(af[fm], bw[fn],
                                                                acc[fm][fn], 0, 0, 0);
      __builtin_amdgcn_s_setprio(0);
    }
    __builtin_amdgcn_sched_barrier(0);
    __builtin_amdgcn_s_barrier();
  }

  // epilogue: D frag layout col=lane&15, row=(lane>>4)*4+r
#pragma unroll
  for (int fn = 0; fn < 4; ++fn) {
    int gcol = g0 + wc * 64 + fn * 16 + lr;
    float bb = bias[gcol];
#pragma unroll
    for (int fm = 0; fm < 4; ++fm) {
#pragma unroll
      for (int r = 0; r < 4; ++r) {
        int t = t0 + wr * 64 + fm * 16 + lg * 4 + r;
        if (t >= Tm) continue;
        Y[((long)b * Tm + t) * N + gcol] = acc[fm][fn][r] + bb;
      }
    }
  }
}

// ---------------------------------------------------------------- MFMA tap-GEMM (day GEMM only)
__global__ __launch_bounds__(256) void mfma_gemm(
    const bf16* __restrict__ A, const bf16* __restrict__ W,
    const float* __restrict__ bias, bf16* __restrict__ Yb,
    const int* __restrict__ dayIdx, long astride, int Ta, int D, int rstride,
    int Tm, int N, long wsg, long dayWStride, int dayBStride) {
  int b = blockIdx.z;
  int t0 = blockIdx.y * 128, g0 = blockIdx.x * 128;
  const bf16* Ab = A + (long)b * astride;
  int di = dayIdx[b];
  long wbase = (long)di * dayWStride;
  int boff = di * dayBStride;
  __shared__ __align__(16) bf16 Al[2][128 * 64];
  __shared__ __align__(16) bf16 Wl[2][128 * 64];
  int tid = threadIdx.x;
  int lane = tid & 63;
  int wave = tid >> 6;
  int wm = (wave >> 1) * 64, wn = (wave & 1) * 64;
  int lr = lane & 15, lg = lane >> 4;
  int srow = tid >> 3, su = tid & 7;
  int niter = D >> 6;
  f32x4 acc[4][4] = {};
  bf16x8 ra[4], rw[4];

  auto issue = [&](int it) {
    int d0 = it << 6;
#pragma unroll
    for (int i = 0; i < 4; ++i) {
      int m = srow + i * 32;
      int t = t0 + m;
      bf16x8 v = {};
      if (t < Tm) v = *reinterpret_cast<const bf16x8*>(Ab + (long)t * rstride + d0 + su * 8);
      ra[i] = v;
      rw[i] = *reinterpret_cast<const bf16x8*>(W + wbase + (long)(g0 + m) * wsg + d0 + su * 8);
    }
  };
  auto write_lds = [&](int bufi) {
#pragma unroll
    for (int i = 0; i < 4; ++i) {
      int m = srow + i * 32;
      *reinterpret_cast<bf16x8*>(&Al[bufi][m * 64 + ((su ^ (m & 7)) << 3)]) = ra[i];
      *reinterpret_cast<bf16x8*>(&Wl[bufi][m * 64 + ((su ^ (m & 7)) << 3)]) = rw[i];
    }
  };

  issue(0);
  write_lds(0);
  __syncthreads();
  int cur = 0;
  for (int it = 0; it < niter; ++it) {
    if (it + 1 < niter) issue(it + 1);
#pragma unroll
    for (int kc = 0; kc < 2; ++kc) {
      int ub = kc * 4 + lg;
      bf16x8 af[4], bw[4];
#pragma unroll
      for (int f = 0; f < 4; ++f) {
        int m = wm + f * 16 + lr;
        af[f] = *reinterpret_cast<const bf16x8*>(&Al[cur][m * 64 + ((ub ^ (m & 7)) << 3)]);
        int g = wn + f * 16 + lr;
        bw[f] = *reinterpret_cast<const bf16x8*>(&Wl[cur][g * 64 + ((ub ^ (g & 7)) << 3)]);
      }
#pragma unroll
      for (int fm = 0; fm < 4; ++fm)
#pragma unroll
        for (int fn = 0; fn < 4; ++fn)
          acc[fm][fn] = __builtin_amdgcn_mfma_f32_16x16x32_bf16(af[fm], bw[fn],
                                                                acc[fm][fn], 0, 0, 0);
    }
    if (it + 1 < niter) write_lds(cur ^ 1);
    __syncthreads();
    cur ^= 1;
  }
#pragma unroll
  for (int fn = 0; fn < 4; ++fn) {
    int gcol = g0 + wn + fn * 16 + lr;
    float bb = bias[boff + gcol];
#pragma unroll
    for (int fm = 0; fm < 4; ++fm) {
#pragma unroll
      for (int r = 0; r < 4; ++r) {
        int t = t0 + wm + fm * 16 + lg * 4 + r;
        if (t >= Tm) continue;
        float v = acc[fm][fn][r] + bb;
        v = v / (1.f + fabsf(v));
        Yb[((long)b * Tm + t) * N + gcol] = (bf16)v;
      }
    }
  }
}

// ---------------------------------------------------------------- t=0 path: A0 im2col, GEMM partials, reduce
__global__ void build_A0(const bf16* __restrict__ xs, bf16* __restrict__ A0) {
  int idx = blockIdx.x * 256 + threadIdx.x;  // 32*3584
  if (idx >= 32 * 3584) return;
  int b = idx / 3584, j = idx % 3584;
  int d = j / 14, u = j % 14;
  A0[idx] = xs[((long)b * 2000 + u) * 256 + d];
}

__global__ __launch_bounds__(256) void t0_gemm(const bf16* __restrict__ A0,
                                               const bf16* __restrict__ W0b,
                                               float* __restrict__ part) {
  int g0 = blockIdx.x * 128;
  int ks = blockIdx.y;  // 0..6
  int k0 = ks * 512;
  __shared__ __align__(16) bf16 Wl[128 * 64];
  __shared__ __align__(16) bf16 Alds[32 * 64];
  int tid = threadIdx.x;
  int lane = tid & 63, wave = tid >> 6;
  int wn = wave * 32;
  int lr = lane & 15, lg = lane >> 4;
  int srow = tid >> 3, su = tid & 7;
  f32x4 acc[2][2] = {};
  for (int c = 0; c < 8; ++c) {
    int d0 = k0 + c * 64;
#pragma unroll
    for (int i = 0; i < 4; ++i) {
      int m = srow + i * 32;
      *reinterpret_cast<bf16x8*>(&Wl[m * 64 + ((su ^ (m & 7)) << 3)]) =
          *reinterpret_cast<const bf16x8*>(W0b + (long)(g0 + m) * 3584 + d0 + su * 8);
    }
    {
      int m = srow;
      *reinterpret_cast<bf16x8*>(&Alds[m * 64 + ((su ^ (m & 7)) << 3)]) =
          *reinterpret_cast<const bf16x8*>(A0 + (long)m * 3584 + d0 + su * 8);
    }
    __syncthreads();
#pragma unroll
    for (int kc = 0; kc < 2; ++kc) {
      int ub = kc * 4 + lg;
      bf16x8 am[2], bw[2];
#pragma unroll
      for (int f = 0; f < 2; ++f) {
        int m = f * 16 + lr;
        am[f] = *reinterpret_cast<const bf16x8*>(&Alds[m * 64 + ((ub ^ (m & 7)) << 3)]);
        int g = wn + f * 16 + lr;
        bw[f] = *reinterpret_cast<const bf16x8*>(&Wl[g * 64 + ((ub ^ (g & 7)) << 3)]);
      }
#pragma unroll
      for (int fm = 0; fm < 2; ++fm)
#pragma unroll
        for (int fn = 0; fn < 2; ++fn)
          acc[fm][fn] = __builtin_amdgcn_mfma_f32_16x16x32_bf16(am[fm], bw[fn],
                                                                acc[fm][fn], 0, 0, 0);
    }
    __syncthreads();
  }
#pragma unroll
  for (int fn = 0; fn < 2; ++fn) {
    int gcol = g0 + wn + fn * 16 + lr;
#pragma unroll
    for (int fm = 0; fm < 2; ++fm)
#pragma unroll
      for (int r = 0; r < 4; ++r) {
        int brow = fm * 16 + lg * 4 + r;
        part[((long)ks * 32 + brow) * 1536 + gcol] = acc[fm][fn][r];
      }
  }
}

__global__ void t0_reduce(const float* __restrict__ part, const float* __restrict__ b0,
                          float* __restrict__ y, int Tp) {
  int idx = blockIdx.x * 256 + threadIdx.x;  // 32*1536
  if (idx >= 32 * 1536) return;
  int b = idx / 1536, g = idx % 1536;
  float s = b0[g];
#pragma unroll
  for (int k = 0; k < 7; ++k) s += part[((long)k * 32 + b) * 1536 + g];
  y[(long)b * Tp * 1536 + g] = s;
}

// ---------------------------------------------------------------- chunked scan (3 passes)
#define NC 8
#define LC 63
__device__ __forceinline__ float fsig(float x) { return 1.f / (1.f + __expf(-x)); }
__device__ __forceinline__ float ftanh(float x) { return 1.f - 2.f / (1.f + __expf(2.f * x)); }

__global__ __launch_bounds__(256) void scan_pass1(const float* __restrict__ Yv,
                                                  float* __restrict__ Afac,
                                                  float* __restrict__ Bfac, int Tp) {
  int idx = blockIdx.x * 256 + threadIdx.x;  // 8*16384
  int ci = idx >> 14;
  int chain = idx & 16383;
  int b = chain >> 9, hh = chain & 511;
  const float* yb = Yv + (long)b * Tp * 1536 + hh;
  int t0 = ci * LC, t1 = min(t0 + LC, Tp);
  float A = 1.f, Bv = 0.f;
  for (int t = t0; t < t1; ++t) {
    const float* p = yb + (long)t * 1536;
    float z = p[0], f = p[512];
    float fs = fsig(f);
    Bv = fs * ftanh(z) + (1.f - fs) * Bv;
    A *= (1.f - fs);
  }
  Afac[idx] = A;
  Bfac[idx] = Bv;
}

__global__ void scan_pass2(const float* __restrict__ Afac, const float* __restrict__ Bfac,
                           float* __restrict__ cst) {
  int chain = blockIdx.x * 256 + threadIdx.x;  // 16384
  float c = 0.f;
#pragma unroll
  for (int ci = 0; ci < NC; ++ci) {
    cst[ci * 16384 + chain] = c;
    c = Afac[ci * 16384 + chain] * c + Bfac[ci * 16384 + chain];
  }
}

__global__ __launch_bounds__(256) void scan_pass3(const float* __restrict__ Yv,
                                                  const float* __restrict__ cst,
                                                  bf16* __restrict__ H, int Tp) {
  int idx = blockIdx.x * 256 + threadIdx.x;
  int ci = idx >> 14;
  int chain = idx & 16383;
  int b = chain >> 9, hh = chain & 511;
  const float* yb = Yv + (long)b * Tp * 1536 + hh;
  bf16* hb = H + ((long)b * 498 + 1) * 512 + hh;  // padded layout
  int t0 = ci * LC, t1 = min(t0 + LC, Tp);
  float c = cst[ci * 16384 + chain];
  for (int t = t0; t < t1; ++t) {
    const float* p = yb + (long)t * 1536;
    float z = p[0], f = p[512], o = p[1024];
    float fs = fsig(f);
    c = fs * ftanh(z) + (1.f - fs) * c;
    hb[(long)t * 512] = (bf16)(fsig(o) * c);
  }
}

// ---------------------------------------------------------------- layernorm + output GEMM
__global__ __launch_bounds__(256) void ln_out_kernel(
    const bf16* __restrict__ Hs, const float* __restrict__ gamma,
    const float* __restrict__ beta, const float* __restrict__ Wo,
    const float* __restrict__ bo, float* __restrict__ Out) {
  long bt = blockIdx.x;
  int b = (int)(bt / 497), t = (int)(bt % 497);
  const bf16* hrow = Hs + ((long)b * 498 + 1 + t) * 512;
  int tid = threadIdx.x;
  float v0 = (float)hrow[tid], v1 = (float)hrow[tid + 256];
  float s = v0 + v1, s2 = v0 * v0 + v1 * v1;
#pragma unroll
  for (int d = 32; d; d >>= 1) {
    s += __shfl_down(s, d);
    s2 += __shfl_down(s2, d);
  }
  __shared__ float rs[4], rs2[4];
  int wid = tid >> 6, lane = tid & 63;
  if (lane == 0) {
    rs[wid] = s;
    rs2[wid] = s2;
  }
  __syncthreads();
  float sum = rs[0] + rs[1] + rs[2] + rs[3];
  float sum2 = rs2[0] + rs2[1] + rs2[2] + rs2[3];
  float mu = sum * (1.f / 512.f);
  float var = sum2 * (1.f / 512.f) - mu * mu;
  float rstd = rsqrtf(var + 1e-5f);
  __shared__ float hl[512];
  hl[tid] = (v0 - mu) * rstd * gamma[tid] + beta[tid];
  hl[tid + 256] = (v1 - mu) * rstd * gamma[tid + 256] + beta[tid + 256];
  __syncthreads();
  const float4* hp = reinterpret_cast<const float4*>(&hl[lane * 8]);
  float4 h0v = hp[0], h1v = hp[1];
  for (int c = wid; c < 41; c += 4) {
    const float4* wp = reinterpret_cast<const float4*>(Wo + (long)c * 512 + lane * 8);
    float4 w0v = wp[0], w1v = wp[1];
    float a = w0v.x * h0v.x + w0v.y * h0v.y + w0v.z * h0v.z + w0v.w * h0v.w +
              w1v.x * h1v.x + w1v.y * h1v.y + w1v.z * h1v.z + w1v.w * h1v.w;
#pragma unroll
    for (int d = 32; d; d >>= 1) a += __shfl_down(a, d);
    if (lane == 0) Out[bt * 41 + c] = a + bo[c];
  }
}

// ---------------------------------------------------------------- launch
extern "C" void kernel_launch(void* const* d_in, const int* in_sizes, int n_in,
                              void* d_out, int out_size, void* d_ws, size_t ws_size,
                              hipStream_t stream) {
  const float* neuralInput = (const float*)d_in[0];
  const int* dayIdx = (const int*)d_in[1];
  const float* dayWeights = (const float*)d_in[2];
  const float* dayBias = (const float*)d_in[3];
  const float* w0 = (const float*)d_in[4];
  const float* b0 = (const float*)d_in[5];
  const float* w_rest = (const float*)d_in[6];
  const float* b_rest = (const float*)d_in[7];
  const float* ln_gamma = (const float*)d_in[8];
  const float* ln_beta = (const float*)d_in[9];
  const float* w_out = (const float*)d_in[10];
  const float* b_out = (const float*)d_in[11];
  float* out = (float*)d_out;

  const int B = 32, T = 2000, Tp = 497;

  char* p = (char*)d_ws;
  float* y = (float*)p;   p += 97714176;   // 32*497*1536 fp32
  bf16* xs0b = (bf16*)p;  p += 32768000;   // 32*2000*256
  bf16* xs = (bf16*)p;    p += 32768000;   // 32*2000*256
  bf16* Vb = (bf16*)p;    p += 14155776;   // 18*1536*256
  bf16* dWb = (bf16*)p;   p += 3145728;    // 24*256*256
  bf16* wrb = (bf16*)p;   p += 6291456;    // 2*1536*1024 (halves swapped)
  bf16* w0b = (bf16*)p;   p += 11010048;   // 1536*3584 (W1 half)
  bf16* A0 = (bf16*)p;    p += 229376;     // 32*3584
  float* part = (float*)p; p += 1376256;   // 7*32*1536
  bf16* h1s = (bf16*)p;   p += 16320512;   // 32*498*512 (per-b pad row)
  bf16* h2s = (bf16*)p;   p += 16320512;
  float* Afac = (float*)p; p += 524288;    // 8*16384
  float* Bfac = (float*)p; p += 524288;
  float* cst = (float*)p;  p += 524288;
  float* zpage = (float*)p; p += 256;      // zero page for masked loads

  const int LDS3 = 3 * 49152;

  hipLaunchKernelGGL(zero_pads, dim3(64), dim3(256), 0, stream, h1s, h2s, zpage);
  hipLaunchKernelGGL(gauss_kernel, dim3((T + GT - 1) / GT, B), dim3(256), 0, stream,
                     neuralInput, xs0b, T);
  hipLaunchKernelGGL(transpose_day, dim3(4, 4, 24), dim3(256), 0, stream, dayWeights, dWb);
  hipLaunchKernelGGL(buildV_kernel, dim3((18L * 1536 * 256 + 255) / 256), dim3(256), 0,
                     stream, w0, Vb);
  hipLaunchKernelGGL(conv_wrest, dim3((2L * 1536 * 1024 + 255) / 256), dim3(256), 0,
                     stream, w_rest, wrb, 2L * 1536 * 1024);
  hipLaunchKernelGGL(conv_w0half, dim3((1536L * 3584 + 255) / 256), dim3(256), 0,
                     stream, w0, w0b);
  // day GEMM + softsign -> bf16 xs
  hipLaunchKernelGGL(mfma_gemm, dim3(2, 16, B), dim3(256), 0, stream, xs0b, dWb,
                     dayBias, xs, dayIdx, (long)T * 256, T, 256, 256, T, 256,
                     256L, 65536L, 256);
  // t=0 exact path
  hipLaunchKernelGGL(build_A0, dim3((32 * 3584 + 255) / 256), dim3(256), 0, stream, xs, A0);
  hipLaunchKernelGGL(t0_gemm, dim3(12, 7), dim3(256), 0, stream, A0, w0b, part);
  // QRNN0 fused 18-tap GEMM (8-wave counted-vmcnt pipeline)
  hipLaunchKernelGGL(gemm8, dim3(768), dim3(512), LDS3, stream, xs, Vb, b0, y,
                     (const bf16*)zpage, (long)T * 256, T, 256, 256, Tp, 1536, 4,
                     18, -4, 256L, 1536L * 256);
  hipLaunchKernelGGL(t0_reduce, dim3((32 * 1536 + 255) / 256), dim3(256), 0, stream,
                     part, b0, y, Tp);
  // scan 0 -> h1
  hipLaunchKernelGGL(scan_pass1, dim3(512), dim3(256), 0, stream, y, Afac, Bfac, Tp);
  hipLaunchKernelGGL(scan_pass2, dim3(64), dim3(256), 0, stream, Afac, Bfac, cst);
  hipLaunchKernelGGL(scan_pass3, dim3(512), dim3(256), 0, stream, y, cst, h1s, Tp);
  // layers 1,2: single-tap K=1024 GEMM over padded h
  for (int i = 0; i < 2; ++i) {
    bf16* hin = (i == 0) ? h1s : h2s;
    bf16* hout = (i == 0) ? h2s : h1s;
    hipLaunchKernelGGL(gemm8, dim3(768), dim3(512), LDS3, stream, hin,
                       wrb + (long)i * 1536 * 1024, b_rest + (long)i * 1536, y,
                       (const bf16*)zpage, 498L * 512, Tp, 1024, 512, Tp, 1536, 1,
                       1, 0, 1024L, 0L);
    hipLaunchKernelGGL(scan_pass1, dim3(512), dim3(256), 0, stream, y, Afac, Bfac, Tp);
    hipLaunchKernelGGL(scan_pass2, dim3(64), dim3(256), 0, stream, Afac, Bfac, cst);
    hipLaunchKernelGGL(scan_pass3, dim3(512), dim3(256), 0, stream, y, cst, hout, Tp);
  }
  // layernorm + output projection (final h is in h1s)
  hipLaunchKernelGGL(ln_out_kernel, dim3(B * Tp), dim3(256), 0, stream, h1s,
                     ln_gamma, ln_beta, w_out, b_out, out);
}